// Round 1
// baseline (877.137 us; speedup 1.0000x reference)
//
#include <hip/hip_runtime.h>
#include <hip/hip_bf16.h>
#include <math.h>

#define N_NODES 50000
#define N_EDGES 800000
#define NFEAT   512
#define NHID    128
#define NCLASS  40

// ---------------------------------------------------------------------------
// CSR build: histogram -> single-block scan -> scatter
// ---------------------------------------------------------------------------
__global__ void hist_kernel(const int* __restrict__ rows, int* __restrict__ cnt, int n) {
    int i = blockIdx.x * blockDim.x + threadIdx.x;
    if (i < n) atomicAdd(&cnt[rows[i]], 1);
}

// 1 block, 1024 threads: inclusive scan of cnt[0..n-1] -> row_ptr[1..n], cursor[i]=row start
__global__ void scan_kernel(const int* __restrict__ cnt, int* __restrict__ row_ptr,
                            int* __restrict__ cursor, int n) {
    __shared__ int wsum[16];
    __shared__ int sbase_s;
    int t = threadIdx.x;
    int lane = t & 63;
    int w = t >> 6;
    if (t == 0) { sbase_s = 0; row_ptr[0] = 0; }
    __syncthreads();
    for (int start = 0; start < n; start += 1024) {
        int i = start + t;
        int v = (i < n) ? cnt[i] : 0;
        // wave-level inclusive scan (wave64)
        int x = v;
        #pragma unroll
        for (int off = 1; off < 64; off <<= 1) {
            int y = __shfl_up(x, off, 64);
            if (lane >= off) x += y;
        }
        if (lane == 63) wsum[w] = x;
        __syncthreads();
        int wbase = 0;
        for (int j = 0; j < w; ++j) wbase += wsum[j];
        int sbase = sbase_s;
        int incl = sbase + wbase + x;
        if (i < n) { row_ptr[i + 1] = incl; cursor[i] = incl - v; }
        __syncthreads();              // everyone done reading sbase_s / wsum
        if (t == 1023) sbase_s = incl; // chunk total carried forward
        __syncthreads();
    }
}

__global__ void scatter_kernel(const int* __restrict__ rows, const int* __restrict__ cols,
                               const float* __restrict__ vals, int* __restrict__ cursor,
                               int* __restrict__ csr_col, float* __restrict__ csr_val, int n) {
    int i = blockIdx.x * blockDim.x + threadIdx.x;
    if (i < n) {
        int r = rows[i];
        int p = atomicAdd(&cursor[r], 1);
        csr_col[p] = cols[i];
        csr_val[p] = vals[i];
    }
}

// ---------------------------------------------------------------------------
// fp32 GEMM: Og[M,128] = Xg[M,K] @ Wg[K,128].  Block = 256 thr, tile 32x128,
// K-tile 32.  Thread computes 4 rows x 4 cols with float4 LDS reads.
// ---------------------------------------------------------------------------
__global__ __launch_bounds__(256) void gemm128_kernel(const float* __restrict__ Xg,
                                                      const float* __restrict__ Wg,
                                                      float* __restrict__ Og,
                                                      int M, int K) {
    __shared__ float ws[32][128];
    __shared__ float xs[32][36];   // [k][row], pad 36 keeps float4 16B-aligned
    int t = threadIdx.x;
    int row0 = blockIdx.x * 32;
    int c4 = (t & 31) * 4;
    int r4 = (t >> 5) * 4;
    float acc[4][4] = {};

    for (int k0 = 0; k0 < K; k0 += 32) {
        // W tile: 32 k-rows x 128 cols
        #pragma unroll
        for (int i = 0; i < 4; ++i) {
            int kk = (t >> 5) + i * 8;
            float4 wv = *(const float4*)(Wg + (size_t)(k0 + kk) * 128 + c4);
            *(float4*)&ws[kk][c4] = wv;
        }
        // X tile: 32 rows x 32 k (transposed into xs[k][row])
        {
            int r = t >> 3;
            int kk = (t & 7) * 4;
            int gr = row0 + r;
            float4 xv = make_float4(0.f, 0.f, 0.f, 0.f);
            if (gr < M) xv = *(const float4*)(Xg + (size_t)gr * K + k0 + kk);
            xs[kk + 0][r] = xv.x;
            xs[kk + 1][r] = xv.y;
            xs[kk + 2][r] = xv.z;
            xs[kk + 3][r] = xv.w;
        }
        __syncthreads();
        #pragma unroll
        for (int k = 0; k < 32; ++k) {
            float4 wv = *(const float4*)&ws[k][c4];
            float4 xv = *(const float4*)&xs[k][r4];
            float xa[4] = {xv.x, xv.y, xv.z, xv.w};
            float wa[4] = {wv.x, wv.y, wv.z, wv.w};
            #pragma unroll
            for (int ii = 0; ii < 4; ++ii)
                #pragma unroll
                for (int jj = 0; jj < 4; ++jj)
                    acc[ii][jj] = fmaf(xa[ii], wa[jj], acc[ii][jj]);
        }
        __syncthreads();
    }
    #pragma unroll
    for (int ii = 0; ii < 4; ++ii) {
        int row = row0 + r4 + ii;
        if (row < M) {
            float4 o = make_float4(acc[ii][0], acc[ii][1], acc[ii][2], acc[ii][3]);
            *(float4*)(Og + (size_t)row * 128 + c4) = o;
        }
    }
}

// ---------------------------------------------------------------------------
// CSR SpMM (128 features): one wave per row, lane covers cols {lane, lane+64}
// out[r][c] = bias[c] + sum_e val*H[col][c]
// ---------------------------------------------------------------------------
__global__ __launch_bounds__(256) void spmm128_kernel(const float* __restrict__ H,
                                                      const int* __restrict__ row_ptr,
                                                      const int* __restrict__ cols,
                                                      const float* __restrict__ vals,
                                                      const float* __restrict__ bias,
                                                      float* __restrict__ out, int nrows) {
    int wid = (blockIdx.x * blockDim.x + threadIdx.x) >> 6;
    int lane = threadIdx.x & 63;
    if (wid >= nrows) return;
    int s = row_ptr[wid];
    int e = row_ptr[wid + 1];
    float acc0 = bias[lane];
    float acc1 = bias[lane + 64];
    int i = s;
    for (; i + 1 < e; i += 2) {
        int   c0 = cols[i],     c1 = cols[i + 1];
        float v0 = vals[i],     v1 = vals[i + 1];
        const float* h0 = H + (size_t)c0 * 128;
        const float* h1 = H + (size_t)c1 * 128;
        float a0 = h0[lane], a1 = h0[lane + 64];
        float b0 = h1[lane], b1 = h1[lane + 64];
        acc0 = fmaf(v0, a0, acc0); acc1 = fmaf(v0, a1, acc1);
        acc0 = fmaf(v1, b0, acc0); acc1 = fmaf(v1, b1, acc1);
    }
    if (i < e) {
        int c = cols[i]; float v = vals[i];
        const float* hp = H + (size_t)c * 128;
        acc0 = fmaf(v, hp[lane], acc0);
        acc1 = fmaf(v, hp[lane + 64], acc1);
    }
    out[(size_t)wid * 128 + lane] = acc0;
    out[(size_t)wid * 128 + 64 + lane] = acc1;
}

// ---------------------------------------------------------------------------
// PairNorm stats: colsum[128] into stats[0..127], sum of squares into stats[128]
// grid*block must be a multiple of 128 so each thread sticks to one column.
// ---------------------------------------------------------------------------
__global__ __launch_bounds__(256) void stats_kernel(const float* __restrict__ B,
                                                    float* __restrict__ stats, int n) {
    int tid = blockIdx.x * blockDim.x + threadIdx.x;
    int stride = gridDim.x * blockDim.x;   // multiple of 128
    float cs = 0.f, sq = 0.f;
    for (int i = tid; i < n; i += stride) {
        float v = B[i];
        cs += v;
        sq = fmaf(v, v, sq);
    }
    __shared__ float scs[256];
    __shared__ float ssq[256];
    scs[threadIdx.x] = cs;
    ssq[threadIdx.x] = sq;
    __syncthreads();
    if (threadIdx.x < 128) {
        float c2 = scs[threadIdx.x] + scs[threadIdx.x + 128];
        atomicAdd(&stats[threadIdx.x], c2);   // col = threadIdx.x since stride%128==0
        ssq[threadIdx.x] += ssq[threadIdx.x + 128];
    }
    __syncthreads();
    for (int off = 64; off > 0; off >>= 1) {
        if (threadIdx.x < off) ssq[threadIdx.x] += ssq[threadIdx.x + off];
        __syncthreads();
    }
    if (threadIdx.x == 0) atomicAdd(&stats[128], ssq[0]);
}

// 1 block, 128 threads: stats[0..127] -> column means; stats[129] -> 1/rownorm_mean
__global__ void finalize_stats_kernel(float* __restrict__ stats, int nrows) {
    int t = threadIdx.x;
    float mu = stats[t] / (float)nrows;
    __shared__ float smu2[128];
    smu2[t] = mu * mu;
    __syncthreads();
    for (int off = 64; off > 0; off >>= 1) {
        if (t < off) smu2[t] += smu2[t + off];
        __syncthreads();
    }
    if (t == 0) {
        float ms = stats[128] / (float)nrows - smu2[0];
        stats[129] = 1.0f / sqrtf(1e-6f + ms);   // PN_SCALE = 1
    }
    stats[t] = mu;
}

// X[i] = relu((B[i]-mu[c])*scale) + (addResid ? X[i] : 0), float4-vectorized
__global__ __launch_bounds__(256) void pn_apply_kernel(const float* __restrict__ B,
                                                       const float* __restrict__ stats,
                                                       float* __restrict__ X,
                                                       int n4, int addResid) {
    int i = blockIdx.x * blockDim.x + threadIdx.x;
    if (i >= n4) return;
    float4 b = ((const float4*)B)[i];
    int c4 = (i << 2) & 127;
    float s = stats[129];
    float4 m = ((const float4*)stats)[c4 >> 2];
    float4 r = make_float4(0.f, 0.f, 0.f, 0.f);
    if (addResid) r = ((const float4*)X)[i];
    float4 o;
    o.x = fmaxf((b.x - m.x) * s, 0.f) + r.x;
    o.y = fmaxf((b.y - m.y) * s, 0.f) + r.y;
    o.z = fmaxf((b.z - m.z) * s, 0.f) + r.z;
    o.w = fmaxf((b.w - m.w) * s, 0.f) + r.w;
    ((float4*)X)[i] = o;
}

// Pad W_out [128,40] -> Wpad [128,128] (zeros beyond col 40)
__global__ void wpad_kernel(const float* __restrict__ Wout, float* __restrict__ Wpad) {
    int i = blockIdx.x * blockDim.x + threadIdx.x;   // 16384
    int k = i >> 7, c = i & 127;
    Wpad[i] = (c < NCLASS) ? Wout[k * NCLASS + c] : 0.f;
}

// Final SpMM over 40 (padded) features: wave per row, lane < 40 active for store
__global__ __launch_bounds__(256) void spmm_out_kernel(const float* __restrict__ G,
                                                       const int* __restrict__ row_ptr,
                                                       const int* __restrict__ cols,
                                                       const float* __restrict__ vals,
                                                       const float* __restrict__ bias,
                                                       float* __restrict__ out, int nrows) {
    int wid = (blockIdx.x * blockDim.x + threadIdx.x) >> 6;
    int lane = threadIdx.x & 63;
    if (wid >= nrows) return;
    int s = row_ptr[wid];
    int e = row_ptr[wid + 1];
    float acc = (lane < NCLASS) ? bias[lane] : 0.f;
    for (int i = s; i < e; ++i) {
        int c = cols[i];
        float v = vals[i];
        acc = fmaf(v, G[(size_t)c * 128 + lane], acc);   // cols 40..127 are exact zeros
    }
    if (lane < NCLASS) out[(size_t)wid * NCLASS + lane] = acc;
}

// ---------------------------------------------------------------------------
extern "C" void kernel_launch(void* const* d_in, const int* in_sizes, int n_in,
                              void* d_out, int out_size, void* d_ws, size_t ws_size,
                              hipStream_t stream) {
    const float* x        = (const float*)d_in[0];
    const int*   edge_row = (const int*)  d_in[1];
    const int*   edge_col = (const int*)  d_in[2];
    const float* edge_val = (const float*)d_in[3];
    const float* W0 = (const float*)d_in[4];
    const float* b0 = (const float*)d_in[5];
    const float* W1 = (const float*)d_in[6];
    const float* b1 = (const float*)d_in[7];
    const float* W2 = (const float*)d_in[8];
    const float* b2 = (const float*)d_in[9];
    const float* W_out = (const float*)d_in[10];
    const float* b_out = (const float*)d_in[11];
    float* out = (float*)d_out;

    const size_t NH = (size_t)N_NODES * NHID;   // 6,400,000
    float* A    = (float*)d_ws;                 // GEMM output / final G
    float* Bm   = A + NH;                       // SpMM output
    float* X    = Bm + NH;                      // current activations
    float* Wpad = X + NH;                       // 16384
    float* stats = Wpad + 16384;                // 132 floats (mu[128], sumsq, _, scale@129)
    int* cnt     = (int*)(stats + 132);
    int* row_ptr = cnt + N_NODES;
    int* cursor  = row_ptr + N_NODES + 1;
    int* csr_col = cursor + N_NODES;
    float* csr_val = (float*)(csr_col + N_EDGES);

    const int EB = N_EDGES / 256;        // 3125
    const int GEMM_GRID = (N_NODES + 31) / 32;   // 1563
    const int SPMM_GRID = (N_NODES + 3) / 4;     // 12500 (4 waves/block)
    const int PN_GRID = (int)(NH / 4 + 255) / 256;

    // --- CSR build (shared by all 4 SpMMs) ---
    hipMemsetAsync(cnt, 0, N_NODES * sizeof(int), stream);
    hist_kernel<<<EB, 256, 0, stream>>>(edge_row, cnt, N_EDGES);
    scan_kernel<<<1, 1024, 0, stream>>>(cnt, row_ptr, cursor, N_NODES);
    scatter_kernel<<<EB, 256, 0, stream>>>(edge_row, edge_col, edge_val, cursor,
                                           csr_col, csr_val, N_EDGES);
    wpad_kernel<<<64, 256, 0, stream>>>(W_out, Wpad);

    // --- layer 0 (K=512, no residual) ---
    gemm128_kernel<<<GEMM_GRID, 256, 0, stream>>>(x, W0, A, N_NODES, NFEAT);
    spmm128_kernel<<<SPMM_GRID, 256, 0, stream>>>(A, row_ptr, csr_col, csr_val, b0, Bm, N_NODES);
    hipMemsetAsync(stats, 0, 132 * sizeof(float), stream);
    stats_kernel<<<1024, 256, 0, stream>>>(Bm, stats, (int)NH);
    finalize_stats_kernel<<<1, 128, 0, stream>>>(stats, N_NODES);
    pn_apply_kernel<<<PN_GRID, 256, 0, stream>>>(Bm, stats, X, (int)(NH / 4), 0);

    // --- layers 1,2 (K=128, residual) ---
    const float* Ws[2] = {W1, W2};
    const float* bs[2] = {b1, b2};
    for (int l = 0; l < 2; ++l) {
        gemm128_kernel<<<GEMM_GRID, 256, 0, stream>>>(X, Ws[l], A, N_NODES, NHID);
        spmm128_kernel<<<SPMM_GRID, 256, 0, stream>>>(A, row_ptr, csr_col, csr_val, bs[l], Bm, N_NODES);
        hipMemsetAsync(stats, 0, 132 * sizeof(float), stream);
        stats_kernel<<<1024, 256, 0, stream>>>(Bm, stats, (int)NH);
        finalize_stats_kernel<<<1, 128, 0, stream>>>(stats, N_NODES);
        pn_apply_kernel<<<PN_GRID, 256, 0, stream>>>(Bm, stats, X, (int)(NH / 4), 1);
    }

    // --- output head: G = X @ Wpad (cols>=40 zero), then SpMM + b_out ---
    gemm128_kernel<<<GEMM_GRID, 256, 0, stream>>>(X, Wpad, A, N_NODES, NHID);
    spmm_out_kernel<<<SPMM_GRID, 256, 0, stream>>>(A, row_ptr, csr_col, csr_val, b_out,
                                                   out, N_NODES);
}

// Round 2
// 660.695 us; speedup vs baseline: 1.3276x; 1.3276x over previous
//
#include <hip/hip_runtime.h>
#include <hip/hip_bf16.h>
#include <math.h>

#define N_NODES 50000
#define N_EDGES 800000
#define NFEAT   512
#define NHID    128
#define NCLASS  40

typedef short bf16x8 __attribute__((ext_vector_type(8)));
typedef float f32x4  __attribute__((ext_vector_type(4)));

// ---------------------------------------------------------------------------
// CSR build: histogram -> single-block scan -> scatter
// ---------------------------------------------------------------------------
__global__ void hist_kernel(const int* __restrict__ rows, int* __restrict__ cnt, int n) {
    int i = blockIdx.x * blockDim.x + threadIdx.x;
    if (i < n) atomicAdd(&cnt[rows[i]], 1);
}

__global__ void scan_kernel(const int* __restrict__ cnt, int* __restrict__ row_ptr,
                            int* __restrict__ cursor, int n) {
    __shared__ int wsum[16];
    __shared__ int sbase_s;
    int t = threadIdx.x;
    int lane = t & 63;
    int w = t >> 6;
    if (t == 0) { sbase_s = 0; row_ptr[0] = 0; }
    __syncthreads();
    for (int start = 0; start < n; start += 1024) {
        int i = start + t;
        int v = (i < n) ? cnt[i] : 0;
        int x = v;
        #pragma unroll
        for (int off = 1; off < 64; off <<= 1) {
            int y = __shfl_up(x, off, 64);
            if (lane >= off) x += y;
        }
        if (lane == 63) wsum[w] = x;
        __syncthreads();
        int wbase = 0;
        for (int j = 0; j < w; ++j) wbase += wsum[j];
        int sbase = sbase_s;
        int incl = sbase + wbase + x;
        if (i < n) { row_ptr[i + 1] = incl; cursor[i] = incl - v; }
        __syncthreads();
        if (t == 1023) sbase_s = incl;
        __syncthreads();
    }
}

__global__ void scatter_kernel(const int* __restrict__ rows, const int* __restrict__ cols,
                               const float* __restrict__ vals, int* __restrict__ cursor,
                               int* __restrict__ csr_col, float* __restrict__ csr_val, int n) {
    int i = blockIdx.x * blockDim.x + threadIdx.x;
    if (i < n) {
        int r = rows[i];
        int p = atomicAdd(&cursor[r], 1);
        csr_col[p] = cols[i];
        csr_val[p] = vals[i];
    }
}

// ---------------------------------------------------------------------------
// fp32 -> bf16 elementwise convert (float4 in, 4x bf16 out)
// ---------------------------------------------------------------------------
__global__ __launch_bounds__(256) void cvt_bf16_kernel(const float* __restrict__ in,
                                                       __hip_bfloat16* __restrict__ out, int n) {
    int i = (blockIdx.x * blockDim.x + threadIdx.x) * 4;
    if (i >= n) return;
    float4 v = *(const float4*)(in + i);
    __hip_bfloat16 o[4] = {__float2bfloat16(v.x), __float2bfloat16(v.y),
                           __float2bfloat16(v.z), __float2bfloat16(v.w)};
    *(ushort4*)(out + i) = *(ushort4*)o;
}

// Wt[n*K + k] = (n < Nsrc) ? W[k*Nsrc + n] : 0, converted to bf16
__global__ __launch_bounds__(256) void wt_cvt_kernel(const float* __restrict__ W,
                                                     __hip_bfloat16* __restrict__ Wt,
                                                     int K, int N, int Nsrc) {
    int i = blockIdx.x * blockDim.x + threadIdx.x;
    if (i >= N * K) return;
    int k = i / N, n = i % N;
    float v = (n < Nsrc) ? W[k * Nsrc + n] : 0.f;
    Wt[(size_t)n * K + k] = __float2bfloat16(v);
}

// ---------------------------------------------------------------------------
// MFMA bf16 GEMM: Ob[M,BN] = Xb[M,K](bf16) @ Wt[BN,K](bf16, pre-transposed)
// 256 thr = 4 waves, each wave 32x64 via 2x4 tiles of 16x16x32 MFMA.
// LDS rows padded to 72 bf16 (144B): fragment b128 reads are 2-way = free.
// ---------------------------------------------------------------------------
template<int BM, int BN, int K>
__global__ __launch_bounds__(256) void mfma_gemm(const __hip_bfloat16* __restrict__ Xb,
                                                 const __hip_bfloat16* __restrict__ Wt,
                                                 __hip_bfloat16* __restrict__ Ob, int M) {
    constexpr int BK  = 64;
    constexpr int LDK = 72;
    constexpr int WN  = BN / 64;   // waves along n
    __shared__ short As[BM * LDK];
    __shared__ short Bs[BN * LDK];
    int t = threadIdx.x;
    int lane = t & 63;
    int w = t >> 6;
    int wm = w / WN, wn = w % WN;
    int row0 = blockIdx.x * BM;
    int m0 = wm * 32, n0 = wn * 64;
    int l15 = lane & 15, quad = lane >> 4;

    f32x4 acc[2][4] = {};

    for (int k0 = 0; k0 < K; k0 += BK) {
        // stage A tile: BM rows x 64 bf16 (8 x 16B chunks per row)
        #pragma unroll
        for (int idx = t; idx < BM * 8; idx += 256) {
            int r = idx >> 3, c = idx & 7;
            uint4 v = make_uint4(0u, 0u, 0u, 0u);
            if (row0 + r < M)
                v = *(const uint4*)(Xb + (size_t)(row0 + r) * K + k0 + c * 8);
            *(uint4*)(As + r * LDK + c * 8) = v;
        }
        // stage B tile: BN rows x 64 bf16
        #pragma unroll
        for (int idx = t; idx < BN * 8; idx += 256) {
            int r = idx >> 3, c = idx & 7;
            uint4 v = *(const uint4*)(Wt + (size_t)r * K + k0 + c * 8);
            *(uint4*)(Bs + r * LDK + c * 8) = v;
        }
        __syncthreads();
        #pragma unroll
        for (int ks = 0; ks < 2; ++ks) {
            bf16x8 af[2], bfv[4];
            #pragma unroll
            for (int mt = 0; mt < 2; ++mt)
                af[mt] = *(const bf16x8*)(As + (m0 + mt * 16 + l15) * LDK + ks * 32 + quad * 8);
            #pragma unroll
            for (int nt = 0; nt < 4; ++nt)
                bfv[nt] = *(const bf16x8*)(Bs + (n0 + nt * 16 + l15) * LDK + ks * 32 + quad * 8);
            #pragma unroll
            for (int mt = 0; mt < 2; ++mt)
                #pragma unroll
                for (int nt = 0; nt < 4; ++nt)
                    acc[mt][nt] = __builtin_amdgcn_mfma_f32_16x16x32_bf16(
                        af[mt], bfv[nt], acc[mt][nt], 0, 0, 0);
        }
        __syncthreads();
    }
    // epilogue: C/D layout col=lane&15, row=quad*4+reg
    #pragma unroll
    for (int mt = 0; mt < 2; ++mt) {
        #pragma unroll
        for (int reg = 0; reg < 4; ++reg) {
            int row = row0 + m0 + mt * 16 + quad * 4 + reg;
            if (row < M) {
                #pragma unroll
                for (int nt = 0; nt < 4; ++nt)
                    Ob[(size_t)row * BN + n0 + nt * 16 + l15] =
                        __float2bfloat16(acc[mt][nt][reg]);
            }
        }
    }
}

// ---------------------------------------------------------------------------
// CSR SpMM over bf16 H [nrows,128]: wave per row, lane covers features {2l,2l+1}
// ---------------------------------------------------------------------------
__global__ __launch_bounds__(256) void spmm_bf16_kernel(const __hip_bfloat16* __restrict__ H,
                                                        const int* __restrict__ row_ptr,
                                                        const int* __restrict__ cols,
                                                        const float* __restrict__ vals,
                                                        const float* __restrict__ bias,
                                                        float* __restrict__ Bm, int nrows) {
    int wid = (blockIdx.x * blockDim.x + threadIdx.x) >> 6;
    int lane = threadIdx.x & 63;
    if (wid >= nrows) return;
    int s = row_ptr[wid];
    int e = row_ptr[wid + 1];
    float acc0 = bias[2 * lane];
    float acc1 = bias[2 * lane + 1];
    const __hip_bfloat162* H2 = (const __hip_bfloat162*)H;
    int i = s;
    for (; i + 3 < e; i += 4) {
        int   c0 = cols[i],     c1 = cols[i + 1], c2 = cols[i + 2], c3 = cols[i + 3];
        float v0 = vals[i],     v1 = vals[i + 1], v2 = vals[i + 2], v3 = vals[i + 3];
        __hip_bfloat162 h0 = H2[(size_t)c0 * 64 + lane];
        __hip_bfloat162 h1 = H2[(size_t)c1 * 64 + lane];
        __hip_bfloat162 h2 = H2[(size_t)c2 * 64 + lane];
        __hip_bfloat162 h3 = H2[(size_t)c3 * 64 + lane];
        acc0 = fmaf(v0, __bfloat162float(h0.x), acc0); acc1 = fmaf(v0, __bfloat162float(h0.y), acc1);
        acc0 = fmaf(v1, __bfloat162float(h1.x), acc0); acc1 = fmaf(v1, __bfloat162float(h1.y), acc1);
        acc0 = fmaf(v2, __bfloat162float(h2.x), acc0); acc1 = fmaf(v2, __bfloat162float(h2.y), acc1);
        acc0 = fmaf(v3, __bfloat162float(h3.x), acc0); acc1 = fmaf(v3, __bfloat162float(h3.y), acc1);
    }
    for (; i < e; ++i) {
        int c = cols[i]; float v = vals[i];
        __hip_bfloat162 h = H2[(size_t)c * 64 + lane];
        acc0 = fmaf(v, __bfloat162float(h.x), acc0);
        acc1 = fmaf(v, __bfloat162float(h.y), acc1);
    }
    float2 o = make_float2(acc0, acc1);
    *(float2*)(Bm + (size_t)wid * 128 + 2 * lane) = o;
}

// ---------------------------------------------------------------------------
// PairNorm stats on fp32 Bm: colsum[0..127], sumsq -> stats[128]
// ---------------------------------------------------------------------------
__global__ __launch_bounds__(256) void stats_kernel(const float* __restrict__ B,
                                                    float* __restrict__ stats, int n) {
    int tid = blockIdx.x * blockDim.x + threadIdx.x;
    int stride = gridDim.x * blockDim.x;   // multiple of 128
    float cs = 0.f, sq = 0.f;
    for (int i = tid; i < n; i += stride) {
        float v = B[i];
        cs += v;
        sq = fmaf(v, v, sq);
    }
    __shared__ float scs[256];
    __shared__ float ssq[256];
    scs[threadIdx.x] = cs;
    ssq[threadIdx.x] = sq;
    __syncthreads();
    if (threadIdx.x < 128) {
        float c2 = scs[threadIdx.x] + scs[threadIdx.x + 128];
        atomicAdd(&stats[threadIdx.x], c2);
        ssq[threadIdx.x] += ssq[threadIdx.x + 128];
    }
    __syncthreads();
    for (int off = 64; off > 0; off >>= 1) {
        if (threadIdx.x < off) ssq[threadIdx.x] += ssq[threadIdx.x + off];
        __syncthreads();
    }
    if (threadIdx.x == 0) atomicAdd(&stats[128], ssq[0]);
}

__global__ void finalize_stats_kernel(float* __restrict__ stats, int nrows) {
    int t = threadIdx.x;
    float mu = stats[t] / (float)nrows;
    __shared__ float smu2[128];
    smu2[t] = mu * mu;
    __syncthreads();
    for (int off = 64; off > 0; off >>= 1) {
        if (t < off) smu2[t] += smu2[t + off];
        __syncthreads();
    }
    if (t == 0) {
        float ms = stats[128] / (float)nrows - smu2[0];
        stats[129] = 1.0f / sqrtf(1e-6f + ms);   // PN_SCALE = 1
    }
    stats[t] = mu;
}

// Xb[i] (bf16) = relu((Bm[i]-mu[c])*scale) + (addResid ? Xb[i] : 0)
__global__ __launch_bounds__(256) void pn_apply_kernel(const float* __restrict__ B,
                                                       const float* __restrict__ stats,
                                                       __hip_bfloat16* __restrict__ Xb,
                                                       int n4, int addResid) {
    int i = blockIdx.x * blockDim.x + threadIdx.x;
    if (i >= n4) return;
    float4 b = ((const float4*)B)[i];
    int c4 = (i << 2) & 127;
    float s = stats[129];
    float4 m = ((const float4*)stats)[c4 >> 2];
    float r0 = 0.f, r1 = 0.f, r2 = 0.f, r3 = 0.f;
    if (addResid) {
        ushort4 rv = *(const ushort4*)(Xb + (size_t)i * 4);
        __hip_bfloat16* rb = (__hip_bfloat16*)&rv;
        r0 = __bfloat162float(rb[0]); r1 = __bfloat162float(rb[1]);
        r2 = __bfloat162float(rb[2]); r3 = __bfloat162float(rb[3]);
    }
    __hip_bfloat16 o[4];
    o[0] = __float2bfloat16(fmaxf((b.x - m.x) * s, 0.f) + r0);
    o[1] = __float2bfloat16(fmaxf((b.y - m.y) * s, 0.f) + r1);
    o[2] = __float2bfloat16(fmaxf((b.z - m.z) * s, 0.f) + r2);
    o[3] = __float2bfloat16(fmaxf((b.w - m.w) * s, 0.f) + r3);
    *(ushort4*)(Xb + (size_t)i * 4) = *(ushort4*)o;
}

// ---------------------------------------------------------------------------
// Final SpMM over packed 64-wide bf16 G (cols 40..63 are zero): wave per row
// ---------------------------------------------------------------------------
__global__ __launch_bounds__(256) void spmm_out_kernel(const __hip_bfloat16* __restrict__ G,
                                                       const int* __restrict__ row_ptr,
                                                       const int* __restrict__ cols,
                                                       const float* __restrict__ vals,
                                                       const float* __restrict__ bias,
                                                       float* __restrict__ out, int nrows) {
    int wid = (blockIdx.x * blockDim.x + threadIdx.x) >> 6;
    int lane = threadIdx.x & 63;
    if (wid >= nrows) return;
    int s = row_ptr[wid];
    int e = row_ptr[wid + 1];
    float acc = (lane < NCLASS) ? bias[lane] : 0.f;
    int i = s;
    for (; i + 3 < e; i += 4) {
        int   c0 = cols[i],     c1 = cols[i + 1], c2 = cols[i + 2], c3 = cols[i + 3];
        float v0 = vals[i],     v1 = vals[i + 1], v2 = vals[i + 2], v3 = vals[i + 3];
        float g0 = __bfloat162float(G[(size_t)c0 * 64 + lane]);
        float g1 = __bfloat162float(G[(size_t)c1 * 64 + lane]);
        float g2 = __bfloat162float(G[(size_t)c2 * 64 + lane]);
        float g3 = __bfloat162float(G[(size_t)c3 * 64 + lane]);
        acc = fmaf(v0, g0, acc); acc = fmaf(v1, g1, acc);
        acc = fmaf(v2, g2, acc); acc = fmaf(v3, g3, acc);
    }
    for (; i < e; ++i)
        acc = fmaf(vals[i], __bfloat162float(G[(size_t)cols[i] * 64 + lane]), acc);
    if (lane < NCLASS) out[(size_t)wid * NCLASS + lane] = acc;
}

// ---------------------------------------------------------------------------
extern "C" void kernel_launch(void* const* d_in, const int* in_sizes, int n_in,
                              void* d_out, int out_size, void* d_ws, size_t ws_size,
                              hipStream_t stream) {
    const float* x        = (const float*)d_in[0];
    const int*   edge_row = (const int*)  d_in[1];
    const int*   edge_col = (const int*)  d_in[2];
    const float* edge_val = (const float*)d_in[3];
    const float* W0 = (const float*)d_in[4];
    const float* b0 = (const float*)d_in[5];
    const float* W1 = (const float*)d_in[6];
    const float* b1 = (const float*)d_in[7];
    const float* W2 = (const float*)d_in[8];
    const float* b2 = (const float*)d_in[9];
    const float* W_out = (const float*)d_in[10];
    const float* b_out = (const float*)d_in[11];
    float* out = (float*)d_out;

    const size_t NH  = (size_t)N_NODES * NHID;    // 6,400,000
    const size_t NF  = (size_t)N_NODES * NFEAT;   // 25,600,000

    // workspace layout (region0 = Xb0 for layer-0 GEMM, then reused as Bm)
    char* base = (char*)d_ws;
    __hip_bfloat16* Xb0  = (__hip_bfloat16*)base;            // NF bf16 = 51.2MB
    float*          Bm   = (float*)base;                     // NH fp32 = 25.6MB (after GEMM0)
    __hip_bfloat16* Xb   = (__hip_bfloat16*)(base + NF * 2);           // NH bf16
    __hip_bfloat16* A_bf = (__hip_bfloat16*)(base + NF * 2 + NH * 2);  // NH bf16 (also Gp[N,64])
    char* p = base + NF * 2 + NH * 4;
    __hip_bfloat16* Wt0 = (__hip_bfloat16*)p;  p += (size_t)128 * 512 * 2;
    __hip_bfloat16* Wt1 = (__hip_bfloat16*)p;  p += (size_t)128 * 128 * 2;
    __hip_bfloat16* Wt2 = (__hip_bfloat16*)p;  p += (size_t)128 * 128 * 2;
    __hip_bfloat16* Wot = (__hip_bfloat16*)p;  p += (size_t)64 * 128 * 2;
    float* stats  = (float*)p;                 p += 132 * 4 + 8;       // keep 8B align
    int* cnt      = (int*)p;                   p += (size_t)N_NODES * 4;
    int* row_ptr  = (int*)p;                   p += (size_t)(N_NODES + 1) * 4;
    int* cursor   = (int*)p;                   p += (size_t)N_NODES * 4;
    int* csr_col  = (int*)p;                   p += (size_t)N_EDGES * 4;
    float* csr_val = (float*)p;

    const int EB = N_EDGES / 256;                 // 3125
    const int SPMM_GRID = (N_NODES + 3) / 4;      // 12500 (4 waves/block)
    const int PN_GRID = (int)(NH / 4 + 255) / 256;

    // --- weight/input conversion ---
    cvt_bf16_kernel<<<(int)(NF / 4 + 255) / 256, 256, 0, stream>>>(x, Xb0, (int)NF);
    wt_cvt_kernel<<<(512 * 128 + 255) / 256, 256, 0, stream>>>(W0, Wt0, 512, 128, 128);
    wt_cvt_kernel<<<(128 * 128 + 255) / 256, 256, 0, stream>>>(W1, Wt1, 128, 128, 128);
    wt_cvt_kernel<<<(128 * 128 + 255) / 256, 256, 0, stream>>>(W2, Wt2, 128, 128, 128);
    wt_cvt_kernel<<<(128 * 64 + 255) / 256, 256, 0, stream>>>(W_out, Wot, 128, 64, 40);

    // --- CSR build (shared by all 4 SpMMs) ---
    hipMemsetAsync(cnt, 0, N_NODES * sizeof(int), stream);
    hist_kernel<<<EB, 256, 0, stream>>>(edge_row, cnt, N_EDGES);
    scan_kernel<<<1, 1024, 0, stream>>>(cnt, row_ptr, cursor, N_NODES);
    scatter_kernel<<<EB, 256, 0, stream>>>(edge_row, edge_col, edge_val, cursor,
                                           csr_col, csr_val, N_EDGES);

    // --- layer 0 (K=512, no residual). GEMM reads Xb0 then region becomes Bm.
    mfma_gemm<64, 128, 512><<<(N_NODES + 63) / 64, 256, 0, stream>>>(Xb0, Wt0, A_bf, N_NODES);
    spmm_bf16_kernel<<<SPMM_GRID, 256, 0, stream>>>(A_bf, row_ptr, csr_col, csr_val, b0, Bm, N_NODES);
    hipMemsetAsync(stats, 0, 132 * sizeof(float), stream);
    stats_kernel<<<1024, 256, 0, stream>>>(Bm, stats, (int)NH);
    finalize_stats_kernel<<<1, 128, 0, stream>>>(stats, N_NODES);
    pn_apply_kernel<<<PN_GRID, 256, 0, stream>>>(Bm, stats, Xb, (int)(NH / 4), 0);

    // --- layers 1,2 (K=128, residual) ---
    const __hip_bfloat16* Wts[2] = {Wt1, Wt2};
    const float* bs[2] = {b1, b2};
    for (int l = 0; l < 2; ++l) {
        mfma_gemm<64, 128, 128><<<(N_NODES + 63) / 64, 256, 0, stream>>>(Xb, Wts[l], A_bf, N_NODES);
        spmm_bf16_kernel<<<SPMM_GRID, 256, 0, stream>>>(A_bf, row_ptr, csr_col, csr_val, bs[l], Bm, N_NODES);
        hipMemsetAsync(stats, 0, 132 * sizeof(float), stream);
        stats_kernel<<<1024, 256, 0, stream>>>(Bm, stats, (int)NH);
        finalize_stats_kernel<<<1, 128, 0, stream>>>(stats, N_NODES);
        pn_apply_kernel<<<PN_GRID, 256, 0, stream>>>(Bm, stats, Xb, (int)(NH / 4), 1);
    }

    // --- output head: Gp[N,64] = Xb @ Wot^T (cols>=40 zero), then SpMM + b_out
    mfma_gemm<128, 64, 128><<<(N_NODES + 127) / 128, 256, 0, stream>>>(Xb, Wot, A_bf, N_NODES);
    spmm_out_kernel<<<SPMM_GRID, 256, 0, stream>>>(A_bf, row_ptr, csr_col, csr_val, b_out,
                                                   out, N_NODES);
}

// Round 3
// 571.313 us; speedup vs baseline: 1.5353x; 1.1564x over previous
//
#include <hip/hip_runtime.h>
#include <hip/hip_bf16.h>
#include <math.h>

#define N_NODES 50000
#define N_EDGES 800000
#define NFEAT   512
#define NHID    128
#define NCLASS  40
#define NB_STATS 256

typedef short bf16x8 __attribute__((ext_vector_type(8)));
typedef float f32x4  __attribute__((ext_vector_type(4)));

// ---------------------------------------------------------------------------
// CSR build: histogram -> single-block scan -> scatter
// ---------------------------------------------------------------------------
__global__ void hist_kernel(const int* __restrict__ rows, int* __restrict__ cnt, int n) {
    int i = blockIdx.x * blockDim.x + threadIdx.x;
    if (i < n) atomicAdd(&cnt[rows[i]], 1);
}

__global__ void scan_kernel(const int* __restrict__ cnt, int* __restrict__ row_ptr,
                            int* __restrict__ cursor, int n) {
    __shared__ int wsum[16];
    __shared__ int sbase_s;
    int t = threadIdx.x;
    int lane = t & 63;
    int w = t >> 6;
    if (t == 0) { sbase_s = 0; row_ptr[0] = 0; }
    __syncthreads();
    for (int start = 0; start < n; start += 1024) {
        int i = start + t;
        int v = (i < n) ? cnt[i] : 0;
        int x = v;
        #pragma unroll
        for (int off = 1; off < 64; off <<= 1) {
            int y = __shfl_up(x, off, 64);
            if (lane >= off) x += y;
        }
        if (lane == 63) wsum[w] = x;
        __syncthreads();
        int wbase = 0;
        for (int j = 0; j < w; ++j) wbase += wsum[j];
        int sbase = sbase_s;
        int incl = sbase + wbase + x;
        if (i < n) { row_ptr[i + 1] = incl; cursor[i] = incl - v; }
        __syncthreads();
        if (t == 1023) sbase_s = incl;
        __syncthreads();
    }
}

__global__ void scatter_kernel(const int* __restrict__ rows, const int* __restrict__ cols,
                               const float* __restrict__ vals, int* __restrict__ cursor,
                               int* __restrict__ csr_col, float* __restrict__ csr_val, int n) {
    int i = blockIdx.x * blockDim.x + threadIdx.x;
    if (i < n) {
        int r = rows[i];
        int p = atomicAdd(&cursor[r], 1);
        csr_col[p] = cols[i];
        csr_val[p] = vals[i];
    }
}

// Wt[n*K + k] = (n < Nsrc) ? W[k*Nsrc + n] : 0, converted to bf16
__global__ __launch_bounds__(256) void wt_cvt_kernel(const float* __restrict__ W,
                                                     __hip_bfloat16* __restrict__ Wt,
                                                     int K, int N, int Nsrc) {
    int i = blockIdx.x * blockDim.x + threadIdx.x;
    if (i >= N * K) return;
    int k = i / N, n = i % N;
    float v = (n < Nsrc) ? W[k * Nsrc + n] : 0.f;
    Wt[(size_t)n * K + k] = __float2bfloat16(v);
}

// ---------------------------------------------------------------------------
// MFMA bf16 GEMM (bf16 A): Ob[M,BN] = Xb[M,K] @ Wt[BN,K]
// 256 thr = 4 waves; wave computes 32x64 via 2x4 tiles of 16x16x32 MFMA.
// ---------------------------------------------------------------------------
template<int BM, int BN, int K>
__global__ __launch_bounds__(256) void mfma_gemm(const __hip_bfloat16* __restrict__ Xb,
                                                 const __hip_bfloat16* __restrict__ Wt,
                                                 __hip_bfloat16* __restrict__ Ob, int M) {
    constexpr int BK  = 64;
    constexpr int LDK = 72;
    constexpr int WN  = BN / 64;
    __shared__ short As[BM * LDK];
    __shared__ short Bs[BN * LDK];
    int t = threadIdx.x;
    int lane = t & 63;
    int w = t >> 6;
    int wm = w / WN, wn = w % WN;
    int row0 = blockIdx.x * BM;
    int m0 = wm * 32, n0 = wn * 64;
    int l15 = lane & 15, quad = lane >> 4;

    f32x4 acc[2][4] = {};

    for (int k0 = 0; k0 < K; k0 += BK) {
        #pragma unroll
        for (int idx = t; idx < BM * 8; idx += 256) {
            int r = idx >> 3, c = idx & 7;
            uint4 v = make_uint4(0u, 0u, 0u, 0u);
            if (row0 + r < M)
                v = *(const uint4*)(Xb + (size_t)(row0 + r) * K + k0 + c * 8);
            *(uint4*)(As + r * LDK + c * 8) = v;
        }
        #pragma unroll
        for (int idx = t; idx < BN * 8; idx += 256) {
            int r = idx >> 3, c = idx & 7;
            uint4 v = *(const uint4*)(Wt + (size_t)r * K + k0 + c * 8);
            *(uint4*)(Bs + r * LDK + c * 8) = v;
        }
        __syncthreads();
        #pragma unroll
        for (int ks = 0; ks < 2; ++ks) {
            bf16x8 af[2], bfv[4];
            #pragma unroll
            for (int mt = 0; mt < 2; ++mt)
                af[mt] = *(const bf16x8*)(As + (m0 + mt * 16 + l15) * LDK + ks * 32 + quad * 8);
            #pragma unroll
            for (int nt = 0; nt < 4; ++nt)
                bfv[nt] = *(const bf16x8*)(Bs + (n0 + nt * 16 + l15) * LDK + ks * 32 + quad * 8);
            #pragma unroll
            for (int mt = 0; mt < 2; ++mt)
                #pragma unroll
                for (int nt = 0; nt < 4; ++nt)
                    acc[mt][nt] = __builtin_amdgcn_mfma_f32_16x16x32_bf16(
                        af[mt], bfv[nt], acc[mt][nt], 0, 0, 0);
        }
        __syncthreads();
    }
    #pragma unroll
    for (int mt = 0; mt < 2; ++mt) {
        #pragma unroll
        for (int reg = 0; reg < 4; ++reg) {
            int row = row0 + m0 + mt * 16 + quad * 4 + reg;
            if (row < M) {
                #pragma unroll
                for (int nt = 0; nt < 4; ++nt)
                    Ob[(size_t)row * BN + n0 + nt * 16 + l15] =
                        __float2bfloat16(acc[mt][nt][reg]);
            }
        }
    }
}

// Same GEMM but A is fp32 in global (x), converted to bf16 during LDS staging.
template<int BM, int BN, int K>
__global__ __launch_bounds__(256) void mfma_gemm_f32a(const float* __restrict__ Xg,
                                                      const __hip_bfloat16* __restrict__ Wt,
                                                      __hip_bfloat16* __restrict__ Ob, int M) {
    constexpr int BK  = 64;
    constexpr int LDK = 72;
    constexpr int WN  = BN / 64;
    __shared__ short As[BM * LDK];
    __shared__ short Bs[BN * LDK];
    int t = threadIdx.x;
    int lane = t & 63;
    int w = t >> 6;
    int wm = w / WN, wn = w % WN;
    int row0 = blockIdx.x * BM;
    int m0 = wm * 32, n0 = wn * 64;
    int l15 = lane & 15, quad = lane >> 4;

    f32x4 acc[2][4] = {};

    for (int k0 = 0; k0 < K; k0 += BK) {
        // A: BM rows x 64 k-floats, convert fp32->bf16 in flight
        #pragma unroll
        for (int idx = t; idx < BM * 16; idx += 256) {
            int r = idx >> 4, c = idx & 15;
            float4 v = make_float4(0.f, 0.f, 0.f, 0.f);
            if (row0 + r < M)
                v = *(const float4*)(Xg + (size_t)(row0 + r) * K + k0 + c * 4);
            __hip_bfloat16 o[4] = {__float2bfloat16(v.x), __float2bfloat16(v.y),
                                   __float2bfloat16(v.z), __float2bfloat16(v.w)};
            *(short4*)(As + r * LDK + c * 4) = *(short4*)o;
        }
        #pragma unroll
        for (int idx = t; idx < BN * 8; idx += 256) {
            int r = idx >> 3, c = idx & 7;
            uint4 v = *(const uint4*)(Wt + (size_t)r * K + k0 + c * 8);
            *(uint4*)(Bs + r * LDK + c * 8) = v;
        }
        __syncthreads();
        #pragma unroll
        for (int ks = 0; ks < 2; ++ks) {
            bf16x8 af[2], bfv[4];
            #pragma unroll
            for (int mt = 0; mt < 2; ++mt)
                af[mt] = *(const bf16x8*)(As + (m0 + mt * 16 + l15) * LDK + ks * 32 + quad * 8);
            #pragma unroll
            for (int nt = 0; nt < 4; ++nt)
                bfv[nt] = *(const bf16x8*)(Bs + (n0 + nt * 16 + l15) * LDK + ks * 32 + quad * 8);
            #pragma unroll
            for (int mt = 0; mt < 2; ++mt)
                #pragma unroll
                for (int nt = 0; nt < 4; ++nt)
                    acc[mt][nt] = __builtin_amdgcn_mfma_f32_16x16x32_bf16(
                        af[mt], bfv[nt], acc[mt][nt], 0, 0, 0);
        }
        __syncthreads();
    }
    #pragma unroll
    for (int mt = 0; mt < 2; ++mt) {
        #pragma unroll
        for (int reg = 0; reg < 4; ++reg) {
            int row = row0 + m0 + mt * 16 + quad * 4 + reg;
            if (row < M) {
                #pragma unroll
                for (int nt = 0; nt < 4; ++nt)
                    Ob[(size_t)row * BN + n0 + nt * 16 + l15] =
                        __float2bfloat16(acc[mt][nt][reg]);
            }
        }
    }
}

// ---------------------------------------------------------------------------
// CSR SpMM over bf16 H [nrows,128]: wave per row (wave-uniform wid -> scalar
// CSR loads), lane covers features {2l,2l+1}. Output bf16.
// ---------------------------------------------------------------------------
__global__ __launch_bounds__(256) void spmm_bf16_kernel(const __hip_bfloat16* __restrict__ H,
                                                        const int* __restrict__ row_ptr,
                                                        const int* __restrict__ cols,
                                                        const float* __restrict__ vals,
                                                        const float* __restrict__ bias,
                                                        __hip_bfloat16* __restrict__ Bm,
                                                        int nrows) {
    int wid = (int)((blockIdx.x * blockDim.x + threadIdx.x) >> 6);
    wid = __builtin_amdgcn_readfirstlane(wid);   // provably wave-uniform -> s_loads
    int lane = threadIdx.x & 63;
    if (wid >= nrows) return;
    int s = row_ptr[wid];
    int e = row_ptr[wid + 1];
    float2 bv = *(const float2*)(bias + 2 * lane);
    float acc0 = bv.x, acc1 = bv.y;
    const __hip_bfloat162* H2 = (const __hip_bfloat162*)H;
    int i = s;
    for (; i + 3 < e; i += 4) {
        int   c0 = cols[i],     c1 = cols[i + 1], c2 = cols[i + 2], c3 = cols[i + 3];
        float v0 = vals[i],     v1 = vals[i + 1], v2 = vals[i + 2], v3 = vals[i + 3];
        __hip_bfloat162 h0 = H2[(size_t)c0 * 64 + lane];
        __hip_bfloat162 h1 = H2[(size_t)c1 * 64 + lane];
        __hip_bfloat162 h2 = H2[(size_t)c2 * 64 + lane];
        __hip_bfloat162 h3 = H2[(size_t)c3 * 64 + lane];
        acc0 = fmaf(v0, __bfloat162float(h0.x), acc0); acc1 = fmaf(v0, __bfloat162float(h0.y), acc1);
        acc0 = fmaf(v1, __bfloat162float(h1.x), acc0); acc1 = fmaf(v1, __bfloat162float(h1.y), acc1);
        acc0 = fmaf(v2, __bfloat162float(h2.x), acc0); acc1 = fmaf(v2, __bfloat162float(h2.y), acc1);
        acc0 = fmaf(v3, __bfloat162float(h3.x), acc0); acc1 = fmaf(v3, __bfloat162float(h3.y), acc1);
    }
    for (; i < e; ++i) {
        int c = cols[i]; float v = vals[i];
        __hip_bfloat162 h = H2[(size_t)c * 64 + lane];
        acc0 = fmaf(v, __bfloat162float(h.x), acc0);
        acc1 = fmaf(v, __bfloat162float(h.y), acc1);
    }
    __hip_bfloat16 o[2] = {__float2bfloat16(acc0), __float2bfloat16(acc1)};
    *(ushort2*)(Bm + (size_t)wid * 128 + 2 * lane) = *(ushort2*)o;
}

// ---------------------------------------------------------------------------
// PairNorm stats on bf16 Bm, no atomics: per-block partials[b][132]
// thread owns column pair (tid&63)*2; grid*block = 65536 (pairs stride % 64 == 0)
// ---------------------------------------------------------------------------
__global__ __launch_bounds__(256) void stats_kernel(const __hip_bfloat16* __restrict__ B,
                                                    float* __restrict__ partials, int n2) {
    int tid = blockIdx.x * blockDim.x + threadIdx.x;
    int stride = NB_STATS * 256;
    const __hip_bfloat162* B2 = (const __hip_bfloat162*)B;
    float cs0 = 0.f, cs1 = 0.f, sq = 0.f;
    for (int j = tid; j < n2; j += stride) {
        __hip_bfloat162 h = B2[j];
        float a = __bfloat162float(h.x), b = __bfloat162float(h.y);
        cs0 += a; cs1 += b;
        sq = fmaf(a, a, sq); sq = fmaf(b, b, sq);
    }
    __shared__ float s0[256], s1[256], ss[256];
    int t = threadIdx.x;
    s0[t] = cs0; s1[t] = cs1; ss[t] = sq;
    __syncthreads();
    if (t < 64) {
        float a = s0[t] + s0[t + 64] + s0[t + 128] + s0[t + 192];
        float b = s1[t] + s1[t + 64] + s1[t + 128] + s1[t + 192];
        float* pb = partials + (size_t)blockIdx.x * 132;
        pb[2 * t] = a;
        pb[2 * t + 1] = b;
    }
    __syncthreads();
    for (int off = 128; off > 0; off >>= 1) {
        if (t < off) ss[t] += ss[t + off];
        __syncthreads();
    }
    if (t == 0) partials[(size_t)blockIdx.x * 132 + 128] = ss[0];
}

// 1 block, 128 threads: reduce partials -> stats[0..127]=mu, stats[129]=1/rownorm_mean
__global__ void finalize_stats_kernel(const float* __restrict__ partials,
                                      float* __restrict__ stats, int nrows) {
    int t = threadIdx.x;
    float cs = 0.f;
    for (int b = 0; b < NB_STATS; ++b) cs += partials[(size_t)b * 132 + t];
    float mu = cs / (float)nrows;
    __shared__ float smu2[128];
    __shared__ float ssq[128];
    float sq = 0.f;
    for (int b = t; b < NB_STATS; b += 128) sq += partials[(size_t)b * 132 + 128];
    smu2[t] = mu * mu;
    ssq[t] = sq;
    __syncthreads();
    for (int off = 64; off > 0; off >>= 1) {
        if (t < off) { smu2[t] += smu2[t + off]; ssq[t] += ssq[t + off]; }
        __syncthreads();
    }
    if (t == 0) {
        float ms = ssq[0] / (float)nrows - smu2[0];
        stats[129] = 1.0f / sqrtf(1e-6f + ms);   // PN_SCALE = 1
    }
    stats[t] = mu;
}

// Xb[i] (bf16) = relu((Bm[i]-mu[c])*scale) + (addResid ? Xb[i] : 0)
__global__ __launch_bounds__(256) void pn_apply_kernel(const __hip_bfloat16* __restrict__ B,
                                                       const float* __restrict__ stats,
                                                       __hip_bfloat16* __restrict__ Xb,
                                                       int n4, int addResid) {
    int i = blockIdx.x * blockDim.x + threadIdx.x;
    if (i >= n4) return;
    ushort4 bv = *(const ushort4*)(B + (size_t)i * 4);
    __hip_bfloat16* bb = (__hip_bfloat16*)&bv;
    int c4 = (i << 2) & 127;
    float s = stats[129];
    float4 m = ((const float4*)stats)[c4 >> 2];
    float r0 = 0.f, r1 = 0.f, r2 = 0.f, r3 = 0.f;
    if (addResid) {
        ushort4 rv = *(const ushort4*)(Xb + (size_t)i * 4);
        __hip_bfloat16* rb = (__hip_bfloat16*)&rv;
        r0 = __bfloat162float(rb[0]); r1 = __bfloat162float(rb[1]);
        r2 = __bfloat162float(rb[2]); r3 = __bfloat162float(rb[3]);
    }
    __hip_bfloat16 o[4];
    o[0] = __float2bfloat16(fmaxf((__bfloat162float(bb[0]) - m.x) * s, 0.f) + r0);
    o[1] = __float2bfloat16(fmaxf((__bfloat162float(bb[1]) - m.y) * s, 0.f) + r1);
    o[2] = __float2bfloat16(fmaxf((__bfloat162float(bb[2]) - m.z) * s, 0.f) + r2);
    o[3] = __float2bfloat16(fmaxf((__bfloat162float(bb[3]) - m.w) * s, 0.f) + r3);
    *(ushort4*)(Xb + (size_t)i * 4) = *(ushort4*)o;
}

// ---------------------------------------------------------------------------
// Final SpMM over packed 64-wide bf16 G (cols 40..63 zero): wave per row
// ---------------------------------------------------------------------------
__global__ __launch_bounds__(256) void spmm_out_kernel(const __hip_bfloat16* __restrict__ G,
                                                       const int* __restrict__ row_ptr,
                                                       const int* __restrict__ cols,
                                                       const float* __restrict__ vals,
                                                       const float* __restrict__ bias,
                                                       float* __restrict__ out, int nrows) {
    int wid = (int)((blockIdx.x * blockDim.x + threadIdx.x) >> 6);
    wid = __builtin_amdgcn_readfirstlane(wid);
    int lane = threadIdx.x & 63;
    if (wid >= nrows) return;
    int s = row_ptr[wid];
    int e = row_ptr[wid + 1];
    float acc = (lane < NCLASS) ? bias[lane] : 0.f;
    int i = s;
    for (; i + 3 < e; i += 4) {
        int   c0 = cols[i],     c1 = cols[i + 1], c2 = cols[i + 2], c3 = cols[i + 3];
        float v0 = vals[i],     v1 = vals[i + 1], v2 = vals[i + 2], v3 = vals[i + 3];
        float g0 = __bfloat162float(G[(size_t)c0 * 64 + lane]);
        float g1 = __bfloat162float(G[(size_t)c1 * 64 + lane]);
        float g2 = __bfloat162float(G[(size_t)c2 * 64 + lane]);
        float g3 = __bfloat162float(G[(size_t)c3 * 64 + lane]);
        acc = fmaf(v0, g0, acc); acc = fmaf(v1, g1, acc);
        acc = fmaf(v2, g2, acc); acc = fmaf(v3, g3, acc);
    }
    for (; i < e; ++i)
        acc = fmaf(vals[i], __bfloat162float(G[(size_t)cols[i] * 64 + lane]), acc);
    if (lane < NCLASS) out[(size_t)wid * NCLASS + lane] = acc;
}

// ---------------------------------------------------------------------------
extern "C" void kernel_launch(void* const* d_in, const int* in_sizes, int n_in,
                              void* d_out, int out_size, void* d_ws, size_t ws_size,
                              hipStream_t stream) {
    const float* x        = (const float*)d_in[0];
    const int*   edge_row = (const int*)  d_in[1];
    const int*   edge_col = (const int*)  d_in[2];
    const float* edge_val = (const float*)d_in[3];
    const float* W0 = (const float*)d_in[4];
    const float* b0 = (const float*)d_in[5];
    const float* W1 = (const float*)d_in[6];
    const float* b1 = (const float*)d_in[7];
    const float* W2 = (const float*)d_in[8];
    const float* b2 = (const float*)d_in[9];
    const float* W_out = (const float*)d_in[10];
    const float* b_out = (const float*)d_in[11];
    float* out = (float*)d_out;

    const size_t NH = (size_t)N_NODES * NHID;   // 6,400,000

    char* p = (char*)d_ws;
    __hip_bfloat16* Xb   = (__hip_bfloat16*)p;  p += NH * 2;   // activations
    __hip_bfloat16* A_bf = (__hip_bfloat16*)p;  p += NH * 2;   // GEMM out / head G
    __hip_bfloat16* Bm   = (__hip_bfloat16*)p;  p += NH * 2;   // SpMM out
    __hip_bfloat16* Wt0 = (__hip_bfloat16*)p;   p += (size_t)128 * 512 * 2;
    __hip_bfloat16* Wt1 = (__hip_bfloat16*)p;   p += (size_t)128 * 128 * 2;
    __hip_bfloat16* Wt2 = (__hip_bfloat16*)p;   p += (size_t)128 * 128 * 2;
    __hip_bfloat16* Wot = (__hip_bfloat16*)p;   p += (size_t)64 * 128 * 2;
    float* stats    = (float*)p;                p += 132 * 4;
    float* partials = (float*)p;                p += (size_t)NB_STATS * 132 * 4;
    int* cnt      = (int*)p;                    p += (size_t)N_NODES * 4;
    int* row_ptr  = (int*)p;                    p += (size_t)(N_NODES + 1) * 4;
    int* cursor   = (int*)p;                    p += (size_t)N_NODES * 4;
    int* csr_col  = (int*)p;                    p += (size_t)N_EDGES * 4;
    float* csr_val = (float*)p;

    const int EB = N_EDGES / 256;                 // 3125
    const int SPMM_GRID = (N_NODES + 3) / 4;      // 12500 (4 waves/block)
    const int PN_GRID = (int)(NH / 4 + 255) / 256;

    // --- weight conversion (tiny) ---
    wt_cvt_kernel<<<(512 * 128 + 255) / 256, 256, 0, stream>>>(W0, Wt0, 512, 128, 128);
    wt_cvt_kernel<<<(128 * 128 + 255) / 256, 256, 0, stream>>>(W1, Wt1, 128, 128, 128);
    wt_cvt_kernel<<<(128 * 128 + 255) / 256, 256, 0, stream>>>(W2, Wt2, 128, 128, 128);
    wt_cvt_kernel<<<(128 * 64 + 255) / 256, 256, 0, stream>>>(W_out, Wot, 128, 64, 40);

    // --- CSR build (shared by all 4 SpMMs) ---
    hipMemsetAsync(cnt, 0, N_NODES * sizeof(int), stream);
    hist_kernel<<<EB, 256, 0, stream>>>(edge_row, cnt, N_EDGES);
    scan_kernel<<<1, 1024, 0, stream>>>(cnt, row_ptr, cursor, N_NODES);
    scatter_kernel<<<EB, 256, 0, stream>>>(edge_row, edge_col, edge_val, cursor,
                                           csr_col, csr_val, N_EDGES);

    // --- layer 0 (K=512, fp32 A converted in staging, no residual) ---
    mfma_gemm_f32a<64, 128, 512><<<(N_NODES + 63) / 64, 256, 0, stream>>>(x, Wt0, A_bf, N_NODES);
    spmm_bf16_kernel<<<SPMM_GRID, 256, 0, stream>>>(A_bf, row_ptr, csr_col, csr_val, b0, Bm, N_NODES);
    stats_kernel<<<NB_STATS, 256, 0, stream>>>(Bm, partials, (int)(NH / 2));
    finalize_stats_kernel<<<1, 128, 0, stream>>>(partials, stats, N_NODES);
    pn_apply_kernel<<<PN_GRID, 256, 0, stream>>>(Bm, stats, Xb, (int)(NH / 4), 0);

    // --- layers 1,2 (K=128, residual) ---
    const __hip_bfloat16* Wts[2] = {Wt1, Wt2};
    const float* bs[2] = {b1, b2};
    for (int l = 0; l < 2; ++l) {
        mfma_gemm<64, 128, 128><<<(N_NODES + 63) / 64, 256, 0, stream>>>(Xb, Wts[l], A_bf, N_NODES);
        spmm_bf16_kernel<<<SPMM_GRID, 256, 0, stream>>>(A_bf, row_ptr, csr_col, csr_val, bs[l], Bm, N_NODES);
        stats_kernel<<<NB_STATS, 256, 0, stream>>>(Bm, partials, (int)(NH / 2));
        finalize_stats_kernel<<<1, 128, 0, stream>>>(partials, stats, N_NODES);
        pn_apply_kernel<<<PN_GRID, 256, 0, stream>>>(Bm, stats, Xb, (int)(NH / 4), 1);
    }

    // --- output head: Gp[N,64] = Xb @ Wot^T (cols>=40 zero), then SpMM + b_out
    mfma_gemm<128, 64, 128><<<(N_NODES + 127) / 128, 256, 0, stream>>>(Xb, Wot, A_bf, N_NODES);
    spmm_out_kernel<<<SPMM_GRID, 256, 0, stream>>>(A_bf, row_ptr, csr_col, csr_val, b_out,
                                                   out, N_NODES);
}